// Round 3
// baseline (2576.304 us; speedup 1.0000x reference)
//
#include <hip/hip_runtime.h>
#include <math.h>

// Problem dims (fixed)
#define NOTES 78
#define IN_DIM 80
#define T_HID 64
#define N_HID 2
#define BATCH 64
#define TLEN 128
#define NSEQ (BATCH * NOTES)          // 4992 time-LSTM sequences
#define NBT  (BATCH * TLEN)           // 8192 note-LSTM sequences
#define SB   8                        // sequences per block in time-LSTM

__device__ __forceinline__ float sigf(float x) {
    return 1.0f / (1.0f + expf(-x));
}
__device__ __forceinline__ float rdlane(float v, int k) {
    return __int_as_float(__builtin_amdgcn_readlane(__float_as_int(v), k));
}

// ---------------------------------------------------------------------------
// Kernel A: fused time-LSTM + note-input projection.  R3: operand broadcasts
// moved OFF the LDS pipe (R2 was LDS-broadcast-bound at ~9200 cyc/step):
//   - x-part waves read x via wave-uniform pointers -> s_load + SGPR-operand fma
//   - h-part waves read h per-lane once (stride-1 ds_read, free) and broadcast
//     via v_readlane (VALU pipe, scales with SIMDs; LDS pipe is per-CU)
// ---------------------------------------------------------------------------
__global__ __launch_bounds__(512, 4)
void time_lstm_fused(const float* __restrict__ x,
                     const float* __restrict__ w_ih,
                     const float* __restrict__ w_hh,
                     const float* __restrict__ b_ih,
                     const float* __restrict__ b_hh,
                     const float* __restrict__ w_ih_n,
                     const float* __restrict__ b_ih_n,
                     const float* __restrict__ b_hh_n,
                     float* __restrict__ gxn) {
    __shared__ __align__(16) float hbuf[SB][T_HID];    // 2 KB
    __shared__ float G0[SB][256];                      // 8 KB  x-part + bias
    __shared__ float G1[SB][256];                      // 8 KB  h-part

    const int tid  = threadIdx.x;
    const int s0   = blockIdx.x * SB;
    const int g    = tid & 255;          // gate row
    const int half = tid >> 8;           // 0: x-part, 1: h-part (wave-uniform)
    const int lane = tid & 63;

    // ---- weight rows in registers (overlaid: max 20 float4 = 80 VGPR) ----
    float4 w[20];
    if (half == 0) {
        const float4* p = (const float4*)(w_ih + (size_t)g * IN_DIM);
#pragma unroll
        for (int j = 0; j < 20; j++) w[j] = p[j];
    } else {
        const float4* p = (const float4*)(w_hh + (size_t)g * T_HID);
#pragma unroll
        for (int j = 0; j < 16; j++) w[j] = p[j];
    }
    const float bias = (half == 0) ? (b_ih[g] + b_hh[g]) : 0.0f;

    // wave-uniform x row base pointers (blockIdx-only math -> SGPRs)
    const float* xs[SB];
#pragma unroll
    for (int s = 0; s < SB; s++)
        xs[s] = x + ((size_t)(s0 + s) * TLEN) * IN_DIM;

    // ---- phase-B / gxn identities ----
    const int su = tid >> 6;             // wave id = seq within block
    const int uu = tid & 63;
    float cst = 0.0f;

    const int nj = (tid >> 3) & 7;
    const int nk = tid & 7;
    float wn[8];
#pragma unroll
    for (int i = 0; i < 8; i++) wn[i] = w_ih_n[nj * 64 + nk * 8 + i];
    const float nbias = b_ih_n[nj] + b_hh_n[nj];
    const int sglb = s0 + su;
    const int nb = sglb / NOTES, nn = sglb % NOTES;
    float* gout = gxn + ((size_t)nn * NBT + (size_t)nb * TLEN) * 8 + nj;

    hbuf[su][uu] = 0.0f;                 // 512 threads = 8*64 exactly
    __syncthreads();

    for (int t = 0; t < TLEN; t++) {
        // ---- gxn for previous step's h (hbuf holds h_{t-1}) ----
        if (t > 0) {
            float p = 0.0f;
#pragma unroll
            for (int i = 0; i < 8; i++) p = fmaf(wn[i], hbuf[su][nk * 8 + i], p);
            p += __shfl_xor(p, 1);
            p += __shfl_xor(p, 2);
            p += __shfl_xor(p, 4);
            if (nk == 0) gout[(size_t)(t - 1) * 8] = p + nbias;
        }

        // ---- phase A: partial gate pre-activations ----
        float acc[SB];
        if (half == 0) {
#pragma unroll
            for (int s = 0; s < SB; s++) acc[s] = bias;
#pragma unroll
            for (int j = 0; j < 20; j++) {
                const float4 wv = w[j];
#pragma unroll
                for (int s = 0; s < SB; s++) {
                    // wave-uniform address -> s_load; fma with SGPR operands
                    const float4 xv = *(const float4*)(xs[s] + (size_t)t * IN_DIM + 4 * j);
                    acc[s] = fmaf(wv.w, xv.w, fmaf(wv.z, xv.z,
                             fmaf(wv.y, xv.y, fmaf(wv.x, xv.x, acc[s]))));
                }
            }
            float* Gp = &G0[0][0];
#pragma unroll
            for (int s = 0; s < SB; s++) Gp[s * 256 + g] = acc[s];
        } else {
            // per-lane copy of h for all 8 seqs (stride-1, conflict-free)
            float hv[SB];
#pragma unroll
            for (int s = 0; s < SB; s++) hv[s] = hbuf[s][lane];
#pragma unroll
            for (int s = 0; s < SB; s++) acc[s] = 0.0f;
#pragma unroll
            for (int k4 = 0; k4 < 16; k4++) {
                const float4 wv = w[k4];
#pragma unroll
                for (int s = 0; s < SB; s++) {
                    const float h0 = rdlane(hv[s], 4 * k4 + 0);
                    const float h1 = rdlane(hv[s], 4 * k4 + 1);
                    const float h2 = rdlane(hv[s], 4 * k4 + 2);
                    const float h3 = rdlane(hv[s], 4 * k4 + 3);
                    acc[s] = fmaf(wv.w, h3, fmaf(wv.z, h2,
                             fmaf(wv.y, h1, fmaf(wv.x, h0, acc[s]))));
                }
            }
            float* Gp = &G1[0][0];
#pragma unroll
            for (int s = 0; s < SB; s++) Gp[s * 256 + g] = acc[s];
        }
        __syncthreads();   // barrier 1: G0/G1 complete

        // ---- phase B: combine partials, activate, update state ----
        {
            const float i_p = G0[su][uu]        + G1[su][uu];
            const float f_p = G0[su][64 + uu]   + G1[su][64 + uu];
            const float g_p = G0[su][128 + uu]  + G1[su][128 + uu];
            const float o_p = G0[su][192 + uu]  + G1[su][192 + uu];
            const float iv = sigf(i_p);
            const float fv = sigf(f_p);
            const float gv = tanhf(g_p);
            const float ov = sigf(o_p);
            cst = fv * cst + iv * gv;
            const float h = ov * tanhf(cst);
            hbuf[su][uu] = h;
        }
        __syncthreads();   // barrier 2: hbuf ready for next step
    }

    // epilogue: gxn for the final h (t = 127)
    {
        float p = 0.0f;
#pragma unroll
        for (int i = 0; i < 8; i++) p = fmaf(wn[i], hbuf[su][nk * 8 + i], p);
        p += __shfl_xor(p, 1);
        p += __shfl_xor(p, 2);
        p += __shfl_xor(p, 4);
        if (nk == 0) gout[(size_t)(TLEN - 1) * 8] = p + nbias;
    }
}

// ---------------------------------------------------------------------------
// Kernel C: note-LSTM scan over 78 notes, fresh zero state per (b,t).
// One thread per bt; outputs buffered in registers, stored as float4 at end.
// ---------------------------------------------------------------------------
__global__ __launch_bounds__(64)
void note_scan_kernel(const float* __restrict__ gxn,
                      const float* __restrict__ w_hh_n,
                      float* __restrict__ out) {
    const int bt = blockIdx.x * 64 + threadIdx.x;         // < 8192
    float wh[16];
#pragma unroll
    for (int i = 0; i < 16; i++) wh[i] = w_hh_n[i];       // [8][2] row-major
    float h0 = 0.f, h1 = 0.f, c0 = 0.f, c1 = 0.f;

    const float4* gp = (const float4*)gxn;                // f4 index = (n*NBT+bt)*2
    float res[2 * NOTES];                                 // output row buffer

    size_t idx = (size_t)bt * 2;
    float4 ga = gp[idx], gb = gp[idx + 1];
    for (int n = 0; n < NOTES; n++) {
        float4 na, nb2;
        if (n + 1 < NOTES) {
            const size_t nidx = ((size_t)(n + 1) * NBT + bt) * 2;
            na  = gp[nidx];
            nb2 = gp[nidx + 1];
        }
        const float i0 = ga.x + wh[0]  * h0 + wh[1]  * h1;
        const float i1 = ga.y + wh[2]  * h0 + wh[3]  * h1;
        const float f0 = ga.z + wh[4]  * h0 + wh[5]  * h1;
        const float f1 = ga.w + wh[6]  * h0 + wh[7]  * h1;
        const float g0 = gb.x + wh[8]  * h0 + wh[9]  * h1;
        const float g1 = gb.y + wh[10] * h0 + wh[11] * h1;
        const float o0 = gb.z + wh[12] * h0 + wh[13] * h1;
        const float o1 = gb.w + wh[14] * h0 + wh[15] * h1;
        c0 = sigf(f0) * c0 + sigf(i0) * tanhf(g0);
        c1 = sigf(f1) * c1 + sigf(i1) * tanhf(g1);
        h0 = sigf(o0) * tanhf(c0);
        h1 = sigf(o1) * tanhf(c1);
        res[n * 2 + 0] = (h0 > 0.5f) ? 1.0f : 0.0f;
        res[n * 2 + 1] = (h1 > 0.5f) ? 1.0f : 0.0f;
        ga = na; gb = nb2;
    }
    float4* op = (float4*)(out + (size_t)bt * (NOTES * N_HID));
#pragma unroll
    for (int j = 0; j < (2 * NOTES) / 4; j++) {
        op[j] = make_float4(res[4 * j], res[4 * j + 1], res[4 * j + 2], res[4 * j + 3]);
    }
}

// ---------------------------------------------------------------------------
extern "C" void kernel_launch(void* const* d_in, const int* in_sizes, int n_in,
                              void* d_out, int out_size, void* d_ws, size_t ws_size,
                              hipStream_t stream) {
    const float* x      = (const float*)d_in[0];  // (64,78,128,80)
    const float* w_ih_t = (const float*)d_in[1];  // (256,80)
    const float* w_hh_t = (const float*)d_in[2];  // (256,64)
    const float* b_ih_t = (const float*)d_in[3];  // (256)
    const float* b_hh_t = (const float*)d_in[4];  // (256)
    const float* w_ih_n = (const float*)d_in[5];  // (8,64)
    const float* w_hh_n = (const float*)d_in[6];  // (8,2)
    const float* b_ih_n = (const float*)d_in[7];  // (8)
    const float* b_hh_n = (const float*)d_in[8];  // (8)
    float* out = (float*)d_out;                   // (64,128,156)

    // workspace: gxn = [78][8192][8] fp32 = 20.4 MB
    float* gxn = (float*)d_ws;

    time_lstm_fused<<<NSEQ / SB, 512, 0, stream>>>(
        x, w_ih_t, w_hh_t, b_ih_t, b_hh_t, w_ih_n, b_ih_n, b_hh_n, gxn);
    note_scan_kernel<<<NBT / 64, 64, 0, stream>>>(gxn, w_hh_n, out);
}

// Round 4
// 1351.509 us; speedup vs baseline: 1.9062x; 1.9062x over previous
//
#include <hip/hip_runtime.h>
#include <math.h>

// Problem dims (fixed)
#define NOTES 78
#define IN_DIM 80
#define T_HID 64
#define N_HID 2
#define BATCH 64
#define TLEN 128
#define NSEQ (BATCH * NOTES)          // 4992 time-LSTM sequences
#define NBT  (BATCH * TLEN)           // 8192 note-LSTM sequences
#define SB   4                        // sequences per block in time-LSTM

__device__ __forceinline__ float sigf(float x) { return 1.0f / (1.0f + expf(-x)); }
__device__ __forceinline__ float rdl(float v, int k) {
    return __int_as_float(__builtin_amdgcn_readlane(__float_as_int(v), k));
}

// ---------------------------------------------------------------------------
// Fused time-LSTM + note-input projection.  R4:
//   - broadcasts via v_readlane (VALU), never via LDS data path (R2 lesson)
//   - 2-gate register tile: 1 readlane feeds 2 fma -> 1.5 inst/MAC
//   - all operands in VGPRs (R3 lesson: scalar-x path caused weight demotion)
//   - block = 256 thr = 2 x-waves + 2 h-waves, SB=4 seqs, 1248 blocks
// ---------------------------------------------------------------------------
__global__ __launch_bounds__(256, 2)
void time_lstm_fused(const float* __restrict__ x,
                     const float* __restrict__ w_ih,
                     const float* __restrict__ w_hh,
                     const float* __restrict__ b_ih,
                     const float* __restrict__ b_hh,
                     const float* __restrict__ w_ih_n,
                     const float* __restrict__ b_ih_n,
                     const float* __restrict__ b_hh_n,
                     float* __restrict__ gxn) {
    __shared__ float hbuf[SB][T_HID];    // 1 KB
    __shared__ float G0[SB][256];        // 4 KB  x-part partial (+bias)
    __shared__ float G1[SB][256];        // 4 KB  h-part partial

    const int tid  = threadIdx.x;
    const int s0   = blockIdx.x * SB;
    const int wid  = tid >> 6;           // 0,1 = x-waves; 2,3 = h-waves
    const int lane = tid & 63;
    const bool isx = (wid < 2);
    const int g0   = ((wid & 1) << 7) | (2 * lane);   // first of 2 owned gates

    // ---- weight registers: 2 gate rows per thread ----
    float4 wA[20], wB[20];               // x: 20 f4 each; h: 16 f4 each
    float biasA = 0.0f, biasB = 0.0f;
    if (isx) {
        const float4* pA = (const float4*)(w_ih + (size_t)g0 * IN_DIM);
        const float4* pB = (const float4*)(w_ih + (size_t)(g0 + 1) * IN_DIM);
#pragma unroll
        for (int j = 0; j < 20; j++) { wA[j] = pA[j]; wB[j] = pB[j]; }
        biasA = b_ih[g0] + b_hh[g0];
        biasB = b_ih[g0 + 1] + b_hh[g0 + 1];
    } else {
        const float4* pA = (const float4*)(w_hh + (size_t)g0 * T_HID);
        const float4* pB = (const float4*)(w_hh + (size_t)(g0 + 1) * T_HID);
#pragma unroll
        for (int j = 0; j < 16; j++) { wA[j] = pA[j]; wB[j] = pB[j]; }
    }

    // x row bases (uniform -> SGPR)
    const float* xr[SB];
#pragma unroll
    for (int s = 0; s < SB; s++) xr[s] = x + (size_t)(s0 + s) * TLEN * IN_DIM;

    // per-lane x operand registers (x-waves): xa = x[k=lane], xb = x[64+(lane&15)]
    float xa[SB], xb[SB];
    if (isx) {
#pragma unroll
        for (int s = 0; s < SB; s++) {
            xa[s] = xr[s][lane];
            xb[s] = xr[s][64 + (lane & 15)];
        }
    }

    // ---- phase-B identity: thread (wid=seq, lane=unit) ----
    float cst = 0.0f;

    // ---- gxn identity: 4 seqs x 8 outs x 8-way k-split = 256 threads ----
    const int su2 = tid >> 6;
    const int nj  = (tid >> 3) & 7;
    const int nk  = tid & 7;
    float wn[8];
#pragma unroll
    for (int i = 0; i < 8; i++) wn[i] = w_ih_n[nj * 64 + nk * 8 + i];
    const float nbias = b_ih_n[nj] + b_hh_n[nj];
    const int sglb = s0 + su2;
    const int nb = sglb / NOTES, nn = sglb % NOTES;
    float* gout = gxn + ((size_t)nn * NBT + (size_t)nb * TLEN) * 8 + nj;

    hbuf[wid][lane] = 0.0f;              // 4 waves x 64 = SB x T_HID exactly
    __syncthreads();

    for (int t = 0; t < TLEN; t++) {
        // ---- gxn for h_{t-1} ----
        if (t > 0) {
            float p = 0.0f;
#pragma unroll
            for (int i = 0; i < 8; i++) p = fmaf(wn[i], hbuf[su2][nk * 8 + i], p);
            p += __shfl_xor(p, 1);
            p += __shfl_xor(p, 2);
            p += __shfl_xor(p, 4);
            if (nk == 0) gout[(size_t)(t - 1) * 8] = p + nbias;
        }

        // prefetch x(t+1) into registers
        float xna[SB], xnb[SB];
        const bool pf = isx && (t + 1 < TLEN);
        if (pf) {
#pragma unroll
            for (int s = 0; s < SB; s++) {
                xna[s] = xr[s][(t + 1) * IN_DIM + lane];
                xnb[s] = xr[s][(t + 1) * IN_DIM + 64 + (lane & 15)];
            }
        }

        // ---- phase A: partial gate pre-activations ----
        if (isx) {
            float aA[SB], aB[SB];
#pragma unroll
            for (int s = 0; s < SB; s++) { aA[s] = biasA; aB[s] = biasB; }
#pragma unroll
            for (int k4 = 0; k4 < 16; k4++) {        // k = 0..63 from xa
                const float4 vA = wA[k4], vB = wB[k4];
#pragma unroll
                for (int s = 0; s < SB; s++) {
                    const float r0 = rdl(xa[s], 4 * k4 + 0);
                    const float r1 = rdl(xa[s], 4 * k4 + 1);
                    const float r2 = rdl(xa[s], 4 * k4 + 2);
                    const float r3 = rdl(xa[s], 4 * k4 + 3);
                    aA[s] = fmaf(vA.x, r0, aA[s]);  aB[s] = fmaf(vB.x, r0, aB[s]);
                    aA[s] = fmaf(vA.y, r1, aA[s]);  aB[s] = fmaf(vB.y, r1, aB[s]);
                    aA[s] = fmaf(vA.z, r2, aA[s]);  aB[s] = fmaf(vB.z, r2, aB[s]);
                    aA[s] = fmaf(vA.w, r3, aA[s]);  aB[s] = fmaf(vB.w, r3, aB[s]);
                }
            }
#pragma unroll
            for (int k4 = 16; k4 < 20; k4++) {       // k = 64..79 from xb (lanes 0..15)
                const float4 vA = wA[k4], vB = wB[k4];
#pragma unroll
                for (int s = 0; s < SB; s++) {
                    const float r0 = rdl(xb[s], 4 * k4 - 64);
                    const float r1 = rdl(xb[s], 4 * k4 - 63);
                    const float r2 = rdl(xb[s], 4 * k4 - 62);
                    const float r3 = rdl(xb[s], 4 * k4 - 61);
                    aA[s] = fmaf(vA.x, r0, aA[s]);  aB[s] = fmaf(vB.x, r0, aB[s]);
                    aA[s] = fmaf(vA.y, r1, aA[s]);  aB[s] = fmaf(vB.y, r1, aB[s]);
                    aA[s] = fmaf(vA.z, r2, aA[s]);  aB[s] = fmaf(vB.z, r2, aB[s]);
                    aA[s] = fmaf(vA.w, r3, aA[s]);  aB[s] = fmaf(vB.w, r3, aB[s]);
                }
            }
#pragma unroll
            for (int s = 0; s < SB; s++) {
                *(float2*)&G0[s][g0] = make_float2(aA[s], aB[s]);
            }
        } else {
            float hv[SB];
#pragma unroll
            for (int s = 0; s < SB; s++) hv[s] = hbuf[s][lane];  // stride-1, conflict-free
            float aA[SB], aB[SB];
#pragma unroll
            for (int s = 0; s < SB; s++) { aA[s] = 0.0f; aB[s] = 0.0f; }
#pragma unroll
            for (int k4 = 0; k4 < 16; k4++) {        // k = 0..63 from hv
                const float4 vA = wA[k4], vB = wB[k4];
#pragma unroll
                for (int s = 0; s < SB; s++) {
                    const float r0 = rdl(hv[s], 4 * k4 + 0);
                    const float r1 = rdl(hv[s], 4 * k4 + 1);
                    const float r2 = rdl(hv[s], 4 * k4 + 2);
                    const float r3 = rdl(hv[s], 4 * k4 + 3);
                    aA[s] = fmaf(vA.x, r0, aA[s]);  aB[s] = fmaf(vB.x, r0, aB[s]);
                    aA[s] = fmaf(vA.y, r1, aA[s]);  aB[s] = fmaf(vB.y, r1, aB[s]);
                    aA[s] = fmaf(vA.z, r2, aA[s]);  aB[s] = fmaf(vB.z, r2, aB[s]);
                    aA[s] = fmaf(vA.w, r3, aA[s]);  aB[s] = fmaf(vB.w, r3, aB[s]);
                }
            }
#pragma unroll
            for (int s = 0; s < SB; s++) {
                *(float2*)&G1[s][g0] = make_float2(aA[s], aB[s]);
            }
        }
        __syncthreads();   // barrier 1: G0/G1 complete

        // ---- phase B: combine, activate, update state (1 (seq,unit)/thread) ----
        {
            const float i_p = G0[wid][lane]       + G1[wid][lane];
            const float f_p = G0[wid][64 + lane]  + G1[wid][64 + lane];
            const float g_p = G0[wid][128 + lane] + G1[wid][128 + lane];
            const float o_p = G0[wid][192 + lane] + G1[wid][192 + lane];
            cst = sigf(f_p) * cst + sigf(i_p) * tanhf(g_p);
            const float h = sigf(o_p) * tanhf(cst);
            hbuf[wid][lane] = h;
        }
        if (pf) {
#pragma unroll
            for (int s = 0; s < SB; s++) { xa[s] = xna[s]; xb[s] = xnb[s]; }
        }
        __syncthreads();   // barrier 2: hbuf ready for next step
    }

    // epilogue: gxn for h_127
    {
        float p = 0.0f;
#pragma unroll
        for (int i = 0; i < 8; i++) p = fmaf(wn[i], hbuf[su2][nk * 8 + i], p);
        p += __shfl_xor(p, 1);
        p += __shfl_xor(p, 2);
        p += __shfl_xor(p, 4);
        if (nk == 0) gout[(size_t)(TLEN - 1) * 8] = p + nbias;
    }
}

// ---------------------------------------------------------------------------
// Note-LSTM scan over 78 notes, fresh zero state per (b,t).
// One thread per bt; outputs buffered in registers, stored as float4 at end.
// ---------------------------------------------------------------------------
__global__ __launch_bounds__(64)
void note_scan_kernel(const float* __restrict__ gxn,
                      const float* __restrict__ w_hh_n,
                      float* __restrict__ out) {
    const int bt = blockIdx.x * 64 + threadIdx.x;         // < 8192
    float wh[16];
#pragma unroll
    for (int i = 0; i < 16; i++) wh[i] = w_hh_n[i];       // [8][2] row-major
    float h0 = 0.f, h1 = 0.f, c0 = 0.f, c1 = 0.f;

    const float4* gp = (const float4*)gxn;                // f4 index = (n*NBT+bt)*2
    float res[2 * NOTES];                                 // output row buffer

    size_t idx = (size_t)bt * 2;
    float4 ga = gp[idx], gb = gp[idx + 1];
    for (int n = 0; n < NOTES; n++) {
        float4 na, nb2;
        if (n + 1 < NOTES) {
            const size_t nidx = ((size_t)(n + 1) * NBT + bt) * 2;
            na  = gp[nidx];
            nb2 = gp[nidx + 1];
        }
        const float i0 = ga.x + wh[0]  * h0 + wh[1]  * h1;
        const float i1 = ga.y + wh[2]  * h0 + wh[3]  * h1;
        const float f0 = ga.z + wh[4]  * h0 + wh[5]  * h1;
        const float f1 = ga.w + wh[6]  * h0 + wh[7]  * h1;
        const float g0 = gb.x + wh[8]  * h0 + wh[9]  * h1;
        const float g1 = gb.y + wh[10] * h0 + wh[11] * h1;
        const float o0 = gb.z + wh[12] * h0 + wh[13] * h1;
        const float o1 = gb.w + wh[14] * h0 + wh[15] * h1;
        c0 = sigf(f0) * c0 + sigf(i0) * tanhf(g0);
        c1 = sigf(f1) * c1 + sigf(i1) * tanhf(g1);
        h0 = sigf(o0) * tanhf(c0);
        h1 = sigf(o1) * tanhf(c1);
        res[n * 2 + 0] = (h0 > 0.5f) ? 1.0f : 0.0f;
        res[n * 2 + 1] = (h1 > 0.5f) ? 1.0f : 0.0f;
        ga = na; gb = nb2;
    }
    float4* op = (float4*)(out + (size_t)bt * (NOTES * N_HID));
#pragma unroll
    for (int j = 0; j < (2 * NOTES) / 4; j++) {
        op[j] = make_float4(res[4 * j], res[4 * j + 1], res[4 * j + 2], res[4 * j + 3]);
    }
}

// ---------------------------------------------------------------------------
extern "C" void kernel_launch(void* const* d_in, const int* in_sizes, int n_in,
                              void* d_out, int out_size, void* d_ws, size_t ws_size,
                              hipStream_t stream) {
    const float* x      = (const float*)d_in[0];  // (64,78,128,80)
    const float* w_ih_t = (const float*)d_in[1];  // (256,80)
    const float* w_hh_t = (const float*)d_in[2];  // (256,64)
    const float* b_ih_t = (const float*)d_in[3];  // (256)
    const float* b_hh_t = (const float*)d_in[4];  // (256)
    const float* w_ih_n = (const float*)d_in[5];  // (8,64)
    const float* w_hh_n = (const float*)d_in[6];  // (8,2)
    const float* b_ih_n = (const float*)d_in[7];  // (8)
    const float* b_hh_n = (const float*)d_in[8];  // (8)
    float* out = (float*)d_out;                   // (64,128,156)

    // workspace: gxn = [78][8192][8] fp32 = 20.4 MB
    float* gxn = (float*)d_ws;

    time_lstm_fused<<<NSEQ / SB, 256, 0, stream>>>(
        x, w_ih_t, w_hh_t, b_ih_t, b_hh_t, w_ih_n, b_ih_n, b_hh_n, gxn);
    note_scan_kernel<<<NBT / 64, 64, 0, stream>>>(gxn, w_hh_n, out);
}